// Round 12
// baseline (306.331 us; speedup 1.0000x reference)
//
#include <hip/hip_runtime.h>
#include <cstddef>

#define D   64
#define L   128
#define NT  64             // ONE wave per block — no __syncthreads anywhere hot
#define ROWS 16            // one M=16 MFMA tile per wave
#define XSS 132            // padded floats
#define HBS 72             // shorts
#define NBLK 512           // 8192 / 16
#define LOG2E 1.4426950408889634f

typedef __attribute__((ext_vector_type(8))) short short8;
typedef __attribute__((ext_vector_type(4))) float floatx4;
typedef __attribute__((ext_vector_type(2))) float f2;

__device__ __forceinline__ float fast_rcp(float x) {
#if defined(__has_builtin)
#if __has_builtin(__builtin_amdgcn_rcpf)
  return __builtin_amdgcn_rcpf(x);
#else
  return 1.0f / x;
#endif
#else
  return 1.0f / x;
#endif
}
__device__ __forceinline__ float ex2(float x) {
#if defined(__has_builtin)
#if __has_builtin(__builtin_amdgcn_exp2f)
  return __builtin_amdgcn_exp2f(x);
#else
  return __builtin_exp2f(x);
#endif
#else
  return __builtin_exp2f(x);
#endif
}
__device__ __forceinline__ f2 ex2_2(f2 v) { return (f2){ex2(v.x), ex2(v.y)}; }
__device__ __forceinline__ f2 rcp_2(f2 v) { return (f2){fast_rcp(v.x), fast_rcp(v.y)}; }
__device__ __forceinline__ float sig_plain(float x) {
  return fast_rcp(1.0f + ex2(-LOG2E * x));
}
__device__ __forceinline__ float tanh2(float G) {   // tanh(x), G = -2log2e*x
  return fmaf(2.0f, fast_rcp(1.0f + ex2(G)), -1.0f);
}
__device__ __forceinline__ unsigned short f2bf_rtne(float f) {
  unsigned int u = __float_as_uint(f);
  u += 0x7fffu + ((u >> 16) & 1u);
  return (unsigned short)(u >> 16);
}

// Barrier-free persistent LSTM scan: ONE wave owns a 16-row chain end to end.
// The wave computes all 256 gate columns itself (16 N-tiles x 2 kk = 32 MFMAs,
// single-bf16 W_hh) and the full elementwise update (16 cells/lane, packed
// fp32 arith + scalar exp2/rcp). The h round-trip is intra-wave LDS: ds_write
// then ds_read from the SAME wave executes in order (per-wave DS queue), so
// there is NO s_barrier in the 128-step loop — the 58% barrier-rendezvous
// stall measured in R11 (2486 cyc/step wall vs ~1030 busy) is removed.
// 512 blocks x 64 thr = 2 waves/CU (~0.5/SIMD): idle SIMDs are the price of
// zero sync. __launch_bounds__(64,1) unlocks 512 VGPRs (Bf[16][2]+acc[16]).
// Gates prescaled by -log2e (-2log2e for g): 5 exp2 + 2 rcp per cell.
__global__ __launch_bounds__(NT, 1)
void lstm_main(const float* __restrict__ x,
               const float* __restrict__ W_num,
               const float* __restrict__ b_num,
               const float* __restrict__ W_ih,
               const float* __restrict__ W_hh,
               const float* __restrict__ b_ih,
               const float* __restrict__ b_hh,
               const float* __restrict__ W_aout,
               const float* __restrict__ b_aout,
               const float* __restrict__ W_fh,
               const float* __restrict__ b_fh,
               const float* __restrict__ W_iouh,
               const float* __restrict__ b_iouh,
               const float* __restrict__ W_oout,
               const float* __restrict__ b_oout,
               float* __restrict__ acc_out,   // [0..63]=fc, [64..127]=hs, [128]=ticket
               float* __restrict__ out)
{
  __shared__ __align__(16) float xs[ROWS * XSS];    // 8.25 KB (x; later h/h_hat)
  __shared__ __align__(16) short hbuf[ROWS * HBS];  // 2.25 KB bf16 h (single buffer)
  __shared__ float sacc[2 * D];
  __shared__ float hobj[D];

  const int lane = threadIdx.x;    // 0..63 — one wave
  const int quad = lane >> 4;
  const int c16  = lane & 15;
  const int k0   = blockIdx.x * ROWS;

  // ---- stage x tile (16 rows x 128), coalesced; zero hbuf ----
  for (int i = lane; i < ROWS * (L / 4); i += NT) {
    int r = i >> 5, c4 = i & 31;
    float4 v = ((const float4*)(x + (size_t)(k0 + r) * L))[c4];
    float* dst = &xs[r * XSS + c4 * 4];
    dst[0] = v.x; dst[1] = v.y; dst[2] = v.z; dst[3] = v.w;
  }
  for (int i = lane; i < ROWS * HBS; i += NT) hbuf[i] = 0;

  // per-gate exp2 prescale (g-gate feeds tanh -> -2log2e)
  const float gscale[4] = {-LOG2E, -LOG2E, -2.0f * LOG2E, -LOG2E};

  // N-tile n = g*4 + e -> gate col j = g*64 + e*16 + c16
  // ---- rank-1 x-projection constants (prescaled) ----
  float An[16], Bc[16];
#pragma unroll
  for (int n = 0; n < 16; ++n) {
    int g = n >> 2, e = n & 3;
    int j = g * 64 + e * 16 + c16;
    const float4* wr = (const float4*)(W_ih + (size_t)j * (2 * D));
    float a = 0.0f, b = b_ih[j] + b_hh[j];
#pragma unroll
    for (int e4 = 0; e4 < 16; ++e4) {
      float4 wv = wr[e4];
      float4 wn = ((const float4*)W_num)[e4];
      float4 bn = ((const float4*)b_num)[e4];
      a = fmaf(wn.x, wv.x, a); a = fmaf(wn.y, wv.y, a);
      a = fmaf(wn.z, wv.z, a); a = fmaf(wn.w, wv.w, a);
      b = fmaf(bn.x, wv.x, b); b = fmaf(bn.y, wv.y, b);
      b = fmaf(bn.z, wv.z, b); b = fmaf(bn.w, wv.w, b);
    }
    An[n] = a * gscale[g]; Bc[n] = b * gscale[g];
  }

  // ---- W_hh B-fragments (prescaled, single RTNE bf16, constant) ----
  short8 Bf[16][2];
#pragma unroll
  for (int n = 0; n < 16; ++n) {
    int g = n >> 2, e = n & 3;
#pragma unroll
    for (int kk = 0; kk < 2; ++kk) {
      const float4* wp = (const float4*)(W_hh + (size_t)(g * 64 + e * 16 + c16) * D
                                         + kk * 32 + quad * 8);
      float wv[8];
      float4 w0 = wp[0], w1 = wp[1];
      wv[0]=w0.x; wv[1]=w0.y; wv[2]=w0.z; wv[3]=w0.w;
      wv[4]=w1.x; wv[5]=w1.y; wv[6]=w1.z; wv[7]=w1.w;
      short8 hi8;
#pragma unroll
      for (int jj = 0; jj < 8; ++jj)
        hi8[jj] = (short)f2bf_rtne(wv[jj] * gscale[g]);
      Bf[n][kk] = hi8;
    }
  }

  const f2 one2 = {1.0f, 1.0f};
  const f2 m2l2 = {-2.0f * LOG2E, -2.0f * LOG2E};
  // pair pe = e*2+rp covers cells (rows quad*4+2rp, quad*4+2rp+1; d=e*16+c16)
  f2 creg2[8], hreg2[8];
#pragma unroll
  for (int pe = 0; pe < 8; ++pe) { creg2[pe] = (f2){0.f, 0.f}; hreg2[pe] = (f2){0.f, 0.f}; }

  for (int t4 = 0; t4 < L; t4 += 4) {
    float4 xq[4];
#pragma unroll
    for (int r = 0; r < 4; ++r)
      xq[r] = *(const float4*)&xs[(quad * 4 + r) * XSS + t4];
#pragma unroll
    for (int u = 0; u < 4; ++u) {
      // A-fragment of h(t-1): intra-wave read of last step's writes (in-order DS)
      short8 ahi[2];
#pragma unroll
      for (int kk = 0; kk < 2; ++kk)
        ahi[kk] = *(const short8*)&hbuf[c16 * HBS + kk * 32 + quad * 8];
      f2 xv01 = {xq[0][u], xq[1][u]};
      f2 xv23 = {xq[2][u], xq[3][u]};
      floatx4 acc[16];
#pragma unroll
      for (int n = 0; n < 16; ++n) {
        f2 A2 = {An[n], An[n]}, B2 = {Bc[n], Bc[n]};
        f2 i01 = A2 * xv01 + B2;
        f2 i23 = A2 * xv23 + B2;
        acc[n] = (floatx4){i01.x, i01.y, i23.x, i23.y};
      }
#pragma unroll
      for (int kk = 0; kk < 2; ++kk) {
#pragma unroll
        for (int n = 0; n < 16; ++n)
          acc[n] = __builtin_amdgcn_mfma_f32_16x16x32_bf16(ahi[kk], Bf[n][kk], acc[n], 0, 0, 0);
      }
      // elementwise: 16 cells/lane = 8 packed pairs
#pragma unroll
      for (int e = 0; e < 4; ++e) {
#pragma unroll
        for (int rp = 0; rp < 2; ++rp) {
          int pe = e * 2 + rp;
          f2 Gi = {acc[0 * 4 + e][2 * rp], acc[0 * 4 + e][2 * rp + 1]};
          f2 Gf = {acc[1 * 4 + e][2 * rp], acc[1 * 4 + e][2 * rp + 1]};
          f2 Gg = {acc[2 * 4 + e][2 * rp], acc[2 * 4 + e][2 * rp + 1]};
          f2 Go = {acc[3 * 4 + e][2 * rp], acc[3 * 4 + e][2 * rp + 1]};
          f2 Ei = ex2_2(Gi), Ef = ex2_2(Gf), Eg = ex2_2(Gg), Eo = ex2_2(Go);
          f2 pf = Ef + one2, pi = Ei + one2, pg = Eg + one2, mg = one2 - Eg;
          f2 pig = pi * pg;
          f2 num = creg2[pe] * pig + mg * pf;
          f2 c2  = num * rcp_2(pf * pig);
          creg2[pe] = c2;
          f2 Ec = ex2_2(c2 * m2l2);
          f2 po = Eo + one2, pc = Ec + one2, mc = one2 - Ec;
          f2 h2 = mc * rcp_2(po * pc);
          hreg2[pe] = h2;
          int row0 = quad * 4 + 2 * rp;
          hbuf[row0 * HBS + e * 16 + c16]       = (short)f2bf_rtne(h2.x);
          hbuf[(row0 + 1) * HBS + e * 16 + c16] = (short)f2bf_rtne(h2.y);
        }
      }
      // no barrier: same wave reads these writes next step (in-order DS queue)
    }
  }

  // ---- tail (all intra-wave; DS in-order, no barriers) ----
  // h fp32 -> xs[row][0..63]
#pragma unroll
  for (int e = 0; e < 4; ++e)
#pragma unroll
    for (int rp = 0; rp < 2; ++rp) {
      int row0 = quad * 4 + 2 * rp, pe = e * 2 + rp;
      xs[row0 * XSS + e * 16 + c16]       = hreg2[pe].x;
      xs[(row0 + 1) * XSS + e * 16 + c16] = hreg2[pe].y;
    }

  float hhat[4][4];   // [e][r]
#pragma unroll
  for (int e = 0; e < 4; ++e) {
    int dcol = e * 16 + c16;
    const float4* wa = (const float4*)(W_aout + (size_t)dcol * D);
    float bb = b_aout[dcol];
#pragma unroll
    for (int r = 0; r < 4; ++r) {
      float a = bb;
      const float* hp = &xs[(quad * 4 + r) * XSS];
#pragma unroll
      for (int e4 = 0; e4 < 16; ++e4) {
        float4 wv = wa[e4];
        a = fmaf(wv.x, hp[e4*4+0], a); a = fmaf(wv.y, hp[e4*4+1], a);
        a = fmaf(wv.z, hp[e4*4+2], a); a = fmaf(wv.w, hp[e4*4+3], a);
      }
      hhat[e][r] = a;
    }
  }
#pragma unroll
  for (int e = 0; e < 4; ++e)
#pragma unroll
    for (int r = 0; r < 4; ++r)
      xs[(quad * 4 + r) * XSS + 64 + e * 16 + c16] = hhat[e][r];

  float pfc[4] = {0.f, 0.f, 0.f, 0.f}, phs[4] = {0.f, 0.f, 0.f, 0.f};
#pragma unroll
  for (int e = 0; e < 4; ++e) {
    int dcol = e * 16 + c16;
    const float4* wf = (const float4*)(W_fh + (size_t)dcol * D);
    float bb = b_fh[dcol];
#pragma unroll
    for (int r = 0; r < 4; ++r) {
      float f = bb;
      const float* hp = &xs[(quad * 4 + r) * XSS + 64];
#pragma unroll
      for (int e4 = 0; e4 < 16; ++e4) {
        float4 wv = wf[e4];
        f = fmaf(wv.x, hp[e4*4+0], f); f = fmaf(wv.y, hp[e4*4+1], f);
        f = fmaf(wv.z, hp[e4*4+2], f); f = fmaf(wv.w, hp[e4*4+3], f);
      }
      int pe = e * 2 + (r >> 1);
      float cc = (r & 1) ? creg2[pe].y : creg2[pe].x;
      pfc[e] = fmaf(sig_plain(f), cc, pfc[e]);
      phs[e] += hhat[e][r];
    }
  }
#pragma unroll
  for (int e = 0; e < 4; ++e) {
    float a = pfc[e], b = phs[e];
    a += __shfl_xor(a, 16); a += __shfl_xor(a, 32);
    b += __shfl_xor(b, 16); b += __shfl_xor(b, 32);
    if (quad == 0) {
      atomicAdd(acc_out + e * 16 + c16, a);
      atomicAdd(acc_out + D + e * 16 + c16, b);
    }
  }

  // ---- last-block finish (single wave; broadcast ticket via shfl) ----
  __threadfence();
  unsigned int prev = 0;
  if (lane == 0)
    prev = __hip_atomic_fetch_add((unsigned int*)(acc_out + 2 * D), 1u,
                                  __ATOMIC_ACQ_REL, __HIP_MEMORY_SCOPE_AGENT);
  prev = (unsigned int)__shfl((int)prev, 0);
  if (prev != NBLK - 1) return;
  __threadfence();
  for (int i = lane; i < 2 * D; i += NT)
    sacc[i] = __hip_atomic_load(acc_out + i, __ATOMIC_RELAXED, __HIP_MEMORY_SCOPE_AGENT);
  {
    const int d = lane;
    float vi = b_iouh[d], vo = b_iouh[D + d], vu = b_iouh[2 * D + d];
    for (int e = 0; e < D; ++e) {
      float hs = sacc[D + e];
      vi = fmaf(W_iouh[(size_t)d * D + e],           hs, vi);
      vo = fmaf(W_iouh[(size_t)(D + d) * D + e],     hs, vo);
      vu = fmaf(W_iouh[(size_t)(2 * D + d) * D + e], hs, vu);
    }
    float c_obj = sig_plain(vi) * tanh2(-2.0f * LOG2E * vu) + sacc[d];
    float h_obj = sig_plain(vo) * tanh2(-2.0f * LOG2E * c_obj);
    hobj[d] = h_obj;
    out[D + d] = c_obj;
  }
  {
    const int d = lane;
    float hh = b_oout[d];
    for (int e = 0; e < D; ++e) hh = fmaf(W_oout[(size_t)d * D + e], hobj[e], hh);
    out[d] = hh;
  }
}

extern "C" void kernel_launch(void* const* d_in, const int* in_sizes, int n_in,
                              void* d_out, int out_size, void* d_ws, size_t ws_size,
                              hipStream_t stream) {
  const float* x      = (const float*)d_in[0];
  const float* W_num  = (const float*)d_in[1];
  const float* b_num  = (const float*)d_in[2];
  const float* W_ih   = (const float*)d_in[3];
  const float* W_hh   = (const float*)d_in[4];
  const float* b_ih   = (const float*)d_in[5];
  const float* b_hh   = (const float*)d_in[6];
  const float* W_aout = (const float*)d_in[7];
  const float* b_aout = (const float*)d_in[8];
  const float* W_fh   = (const float*)d_in[9];
  const float* b_fh   = (const float*)d_in[10];
  const float* W_iouh = (const float*)d_in[11];
  const float* b_iouh = (const float*)d_in[12];
  const float* W_oout = (const float*)d_in[13];
  const float* b_oout = (const float*)d_in[14];
  float* acc = (float*)d_ws;
  float* out = (float*)d_out;

  hipMemsetAsync(d_ws, 0, (2 * D + 1) * sizeof(float), stream);
  lstm_main<<<NBLK, NT, 0, stream>>>(x, W_num, b_num, W_ih, W_hh, b_ih, b_hh,
                                     W_aout, b_aout, W_fh, b_fh,
                                     W_iouh, b_iouh, W_oout, b_oout, acc, out);
}

// Round 13
// 262.461 us; speedup vs baseline: 1.1671x; 1.1671x over previous
//
#include <hip/hip_runtime.h>
#include <cstddef>

#define D    64
#define L    128
#define NT   64            // ONE wave per block — zero barriers in the hot loop
#define CH   4             // chains (batch rows) per wave, at tile-rows {0,4,8,12}
#define XSS  132           // padded floats
#define HBS  72            // shorts
#define NBLK 2048          // 8192 / 4
#define NREP 16            // atomic replica bins
#define LOG2E 1.4426950408889634f

// ws float offsets
#define WS_REP    0                  // 16 x 128 replica accumulators
#define WS_TICKET (NREP * 2 * D)     // 2048
#define WS_AN     2112               // 256 prescaled An
#define WS_BC     2368               // 256 prescaled Bc
#define WS_WHH    2624               // 256x64 bf16 shorts (8192 float slots), 16B-aligned
#define WS_TOTAL  (WS_WHH + 8192)

typedef __attribute__((ext_vector_type(8))) short short8;
typedef __attribute__((ext_vector_type(4))) float floatx4;
typedef __attribute__((ext_vector_type(2))) float f2;

__device__ __forceinline__ float fast_rcp(float x) {
#if defined(__has_builtin)
#if __has_builtin(__builtin_amdgcn_rcpf)
  return __builtin_amdgcn_rcpf(x);
#else
  return 1.0f / x;
#endif
#else
  return 1.0f / x;
#endif
}
__device__ __forceinline__ float ex2(float x) {
#if defined(__has_builtin)
#if __has_builtin(__builtin_amdgcn_exp2f)
  return __builtin_amdgcn_exp2f(x);
#else
  return __builtin_exp2f(x);
#endif
#else
  return __builtin_exp2f(x);
#endif
}
__device__ __forceinline__ f2 ex2_2(f2 v) { return (f2){ex2(v.x), ex2(v.y)}; }
__device__ __forceinline__ f2 rcp_2(f2 v) { return (f2){fast_rcp(v.x), fast_rcp(v.y)}; }
__device__ __forceinline__ float sig_plain(float x) {
  return fast_rcp(1.0f + ex2(-LOG2E * x));
}
__device__ __forceinline__ float tanh2(float G) {   // tanh(x), G = -2log2e*x
  return fmaf(2.0f, fast_rcp(1.0f + ex2(G)), -1.0f);
}
__device__ __forceinline__ unsigned short f2bf_rtne(float f) {
  unsigned int u = __float_as_uint(f);
  u += 0x7fffu + ((u >> 16) & 1u);
  return (unsigned short)(u >> 16);
}

// Setup: per gate-column j, precompute prescaled rank-1 constants An/Bc and
// prescaled single-bf16 W_hh (shared by all 2048 main blocks -> read once).
__global__ void lstm_setup(const float* __restrict__ W_num,
                           const float* __restrict__ b_num,
                           const float* __restrict__ W_ih,
                           const float* __restrict__ W_hh,
                           const float* __restrict__ b_ih,
                           const float* __restrict__ b_hh,
                           float* __restrict__ ws)
{
  const int j = blockIdx.x * 64 + threadIdx.x;   // 0..255
  const int g = j >> 6;
  const float gs = (g == 2) ? (-2.0f * LOG2E) : (-LOG2E);
  float a = 0.0f, b = b_ih[j] + b_hh[j];
  const float* wr = W_ih + (size_t)j * (2 * D);
  for (int e = 0; e < D; ++e) {
    a = fmaf(W_num[e], wr[e], a);
    b = fmaf(b_num[e], wr[e], b);
  }
  ws[WS_AN + j] = a * gs;
  ws[WS_BC + j] = b * gs;
  unsigned short* whh = (unsigned short*)(ws + WS_WHH);
  const float* wh = W_hh + (size_t)j * D;
  for (int e = 0; e < D; ++e)
    whh[j * D + e] = f2bf_rtne(wh[e] * gs);
}

// Barrier-free persistent LSTM: one wave owns 4 complete chains placed at
// tile-rows {0,4,8,12} of the M=16 MFMA tile (other rows pinned zero in hb).
// For every N-tile the real cells are reg 0 of every lane -> each lane owns
// exactly 4 cells (chain=quad, d=16e+c16): elementwise in registers, h
// round-trip is intra-wave LDS (ds in-order, HW-validated in R12 — NO
// s_barrier in the 128-step loop). 2048 blocks x 64 thr = 8 blocks/CU,
// 2 waves/SIMD (launch_bounds(64,2) caps VGPR at 256; ~190 used).
// Cost: 32 MFMAs/wave/step (3/4 tile waste) -> CU matrix pipe ~1241 cyc/step
// is the predicted wall, vs R11's 2486 barrier-rendezvous wall.
__global__ __launch_bounds__(NT, 2)
void lstm_main(const float* __restrict__ x,
               const float* __restrict__ W_aout,
               const float* __restrict__ b_aout,
               const float* __restrict__ W_fh,
               const float* __restrict__ b_fh,
               const float* __restrict__ W_iouh,
               const float* __restrict__ b_iouh,
               const float* __restrict__ W_oout,
               const float* __restrict__ b_oout,
               float* __restrict__ ws,
               float* __restrict__ out)
{
  __shared__ __align__(16) float xs[CH * XSS];      // 2.1 KB (x; later h/h_hat)
  __shared__ __align__(16) short hbuf[16 * HBS];    // 2.25 KB (rows !=0 mod 4 stay 0)
  __shared__ float sacc[2 * D];
  __shared__ float hobj[D];

  const int lane = threadIdx.x;
  const int quad = lane >> 4;       // = this lane's chain
  const int c16  = lane & 15;
  const int k0   = blockIdx.x * CH;

  // ---- stage x (4 chains x 128), zero hbuf ----
  for (int i = lane; i < CH * (L / 4); i += NT) {
    int r = i >> 5, c4 = i & 31;
    float4 v = ((const float4*)(x + (size_t)(k0 + r) * L))[c4];
    float* dst = &xs[r * XSS + c4 * 4];
    dst[0] = v.x; dst[1] = v.y; dst[2] = v.z; dst[3] = v.w;
  }
  for (int i = lane; i < 16 * HBS; i += NT) hbuf[i] = 0;

  // ---- load precomputed constants: N-tile n = g*4+e -> j = g*64+e*16+c16 ----
  float An[16], Bc[16];
  short8 Bf[16][2];
  const unsigned short* whh = (const unsigned short*)(ws + WS_WHH);
#pragma unroll
  for (int n = 0; n < 16; ++n) {
    int g = n >> 2, e = n & 3;
    int j = g * 64 + e * 16 + c16;
    An[n] = ws[WS_AN + j];
    Bc[n] = ws[WS_BC + j];
#pragma unroll
    for (int kk = 0; kk < 2; ++kk)
      Bf[n][kk] = *(const short8*)&whh[j * D + kk * 32 + quad * 8];
  }

  const f2 one2 = {1.0f, 1.0f};
  const f2 m2l2 = {-2.0f * LOG2E, -2.0f * LOG2E};
  f2 creg2[2] = {{0.f, 0.f}, {0.f, 0.f}};   // cells e=(0,1) and (2,3)
  f2 hreg2[2] = {{0.f, 0.f}, {0.f, 0.f}};
  __syncthreads();   // one-time: x/hb staging visible (single wave: trivial)

  const int hrow = (quad * 4) * HBS;   // this lane's chain lives at tile-row 4*quad
  for (int t4 = 0; t4 < L; t4 += 4) {
    float4 xq = *(const float4*)&xs[quad * XSS + t4];   // chain quad's x, 4 steps
#pragma unroll
    for (int u = 0; u < 4; ++u) {
      // A-fragment of h(t-1): lane reads tile-row c16 (real iff c16%4==0)
      short8 ahi[2];
#pragma unroll
      for (int kk = 0; kk < 2; ++kk)
        ahi[kk] = *(const short8*)&hbuf[c16 * HBS + kk * 32 + quad * 8];
      float xv = xq[u];
      floatx4 acc[16];
#pragma unroll
      for (int n = 0; n < 16; ++n) {
        float ci = fmaf(An[n], xv, Bc[n]);
        acc[n] = (floatx4){ci, ci, ci, ci};   // only reg 0 is consumed
      }
#pragma unroll
      for (int kk = 0; kk < 2; ++kk) {
#pragma unroll
        for (int n = 0; n < 16; ++n)
          acc[n] = __builtin_amdgcn_mfma_f32_16x16x32_bf16(ahi[kk], Bf[n][kk], acc[n], 0, 0, 0);
      }
      // elementwise: 4 cells/lane (chain=quad, d=16e+c16), gates = acc[g*4+e][0]
#pragma unroll
      for (int ep = 0; ep < 2; ++ep) {
        int e0 = 2 * ep, e1 = 2 * ep + 1;
        f2 Gi = {acc[0 + e0][0],  acc[0 + e1][0]};
        f2 Gf = {acc[4 + e0][0],  acc[4 + e1][0]};
        f2 Gg = {acc[8 + e0][0],  acc[8 + e1][0]};
        f2 Go = {acc[12 + e0][0], acc[12 + e1][0]};
        f2 Ei = ex2_2(Gi), Ef = ex2_2(Gf), Eg = ex2_2(Gg), Eo = ex2_2(Go);
        f2 pf = Ef + one2, pi = Ei + one2, pg = Eg + one2, mg = one2 - Eg;
        f2 pig = pi * pg;
        f2 num = creg2[ep] * pig + mg * pf;
        f2 c2  = num * rcp_2(pf * pig);
        creg2[ep] = c2;
        f2 Ec = ex2_2(c2 * m2l2);
        f2 po = Eo + one2, pc = Ec + one2, mc = one2 - Ec;
        f2 h2 = mc * rcp_2(po * pc);
        hreg2[ep] = h2;
        hbuf[hrow + 16 * e0 + c16] = (short)f2bf_rtne(h2.x);
        hbuf[hrow + 16 * e1 + c16] = (short)f2bf_rtne(h2.y);
      }
      // no barrier: same wave reads these writes next step (in-order DS queue)
    }
  }

  // ---- tail (intra-wave): h fp32 -> xs[chain][d]; h_hat -> xs[chain][64+d] ----
#pragma unroll
  for (int ep = 0; ep < 2; ++ep) {
    xs[quad * XSS + 16 * (2 * ep)     + c16] = hreg2[ep].x;
    xs[quad * XSS + 16 * (2 * ep + 1) + c16] = hreg2[ep].y;
  }
  float hhat[4];
#pragma unroll
  for (int e = 0; e < 4; ++e) {
    int dcol = e * 16 + c16;
    const float4* wa = (const float4*)(W_aout + (size_t)dcol * D);
    float a = b_aout[dcol];
    const float* hp = &xs[quad * XSS];
#pragma unroll
    for (int e4 = 0; e4 < 16; ++e4) {
      float4 wv = wa[e4];
      a = fmaf(wv.x, hp[e4*4+0], a); a = fmaf(wv.y, hp[e4*4+1], a);
      a = fmaf(wv.z, hp[e4*4+2], a); a = fmaf(wv.w, hp[e4*4+3], a);
    }
    hhat[e] = a;
  }
#pragma unroll
  for (int e = 0; e < 4; ++e) xs[quad * XSS + 64 + e * 16 + c16] = hhat[e];

  float pfc[4], phs[4];
#pragma unroll
  for (int e = 0; e < 4; ++e) {
    int dcol = e * 16 + c16;
    const float4* wf = (const float4*)(W_fh + (size_t)dcol * D);
    float f = b_fh[dcol];
    const float* hp = &xs[quad * XSS + 64];
#pragma unroll
    for (int e4 = 0; e4 < 16; ++e4) {
      float4 wv = wf[e4];
      f = fmaf(wv.x, hp[e4*4+0], f); f = fmaf(wv.y, hp[e4*4+1], f);
      f = fmaf(wv.z, hp[e4*4+2], f); f = fmaf(wv.w, hp[e4*4+3], f);
    }
    float cc = (e & 1) ? creg2[e >> 1].y : creg2[e >> 1].x;
    pfc[e] = sig_plain(f) * cc;
    phs[e] = hhat[e];
  }
  // sum over the block's 4 chains (lanes differing in quad), then replica atomics
  float* rep = ws + WS_REP + (blockIdx.x & (NREP - 1)) * (2 * D);
#pragma unroll
  for (int e = 0; e < 4; ++e) {
    float a = pfc[e], b = phs[e];
    a += __shfl_xor(a, 16); a += __shfl_xor(a, 32);
    b += __shfl_xor(b, 16); b += __shfl_xor(b, 32);
    if (quad == 0) {
      atomicAdd(rep + e * 16 + c16, a);
      atomicAdd(rep + D + e * 16 + c16, b);
    }
  }

  // ---- last-block finish ----
  __threadfence();
  unsigned int prev = 0;
  if (lane == 0)
    prev = __hip_atomic_fetch_add((unsigned int*)(ws + WS_TICKET), 1u,
                                  __ATOMIC_ACQ_REL, __HIP_MEMORY_SCOPE_AGENT);
  prev = (unsigned int)__shfl((int)prev, 0);
  if (prev != NBLK - 1) return;
  __threadfence();
  for (int i = lane; i < 2 * D; i += NT) {
    float s = 0.0f;
    for (int rp = 0; rp < NREP; ++rp)
      s += __hip_atomic_load(ws + WS_REP + rp * (2 * D) + i,
                             __ATOMIC_RELAXED, __HIP_MEMORY_SCOPE_AGENT);
    sacc[i] = s;
  }
  {
    const int d = lane;
    float vi = b_iouh[d], vo = b_iouh[D + d], vu = b_iouh[2 * D + d];
    for (int e = 0; e < D; ++e) {
      float hs = sacc[D + e];
      vi = fmaf(W_iouh[(size_t)d * D + e],           hs, vi);
      vo = fmaf(W_iouh[(size_t)(D + d) * D + e],     hs, vo);
      vu = fmaf(W_iouh[(size_t)(2 * D + d) * D + e], hs, vu);
    }
    float c_obj = sig_plain(vi) * tanh2(-2.0f * LOG2E * vu) + sacc[d];
    float h_obj = sig_plain(vo) * tanh2(-2.0f * LOG2E * c_obj);
    hobj[d] = h_obj;
    out[D + d] = c_obj;
  }
  {
    const int d = lane;
    float hh = b_oout[d];
    for (int e = 0; e < D; ++e) hh = fmaf(W_oout[(size_t)d * D + e], hobj[e], hh);
    out[d] = hh;
  }
}

extern "C" void kernel_launch(void* const* d_in, const int* in_sizes, int n_in,
                              void* d_out, int out_size, void* d_ws, size_t ws_size,
                              hipStream_t stream) {
  const float* x      = (const float*)d_in[0];
  const float* W_num  = (const float*)d_in[1];
  const float* b_num  = (const float*)d_in[2];
  const float* W_ih   = (const float*)d_in[3];
  const float* W_hh   = (const float*)d_in[4];
  const float* b_ih   = (const float*)d_in[5];
  const float* b_hh   = (const float*)d_in[6];
  const float* W_aout = (const float*)d_in[7];
  const float* b_aout = (const float*)d_in[8];
  const float* W_fh   = (const float*)d_in[9];
  const float* b_fh   = (const float*)d_in[10];
  const float* W_iouh = (const float*)d_in[11];
  const float* b_iouh = (const float*)d_in[12];
  const float* W_oout = (const float*)d_in[13];
  const float* b_oout = (const float*)d_in[14];
  float* ws  = (float*)d_ws;
  float* out = (float*)d_out;

  // zero the replica accumulators + ticket (rest of ws is fully overwritten)
  hipMemsetAsync(d_ws, 0, (WS_TICKET + 4) * sizeof(float), stream);
  lstm_setup<<<4, 64, 0, stream>>>(W_num, b_num, W_ih, W_hh, b_ih, b_hh, ws);
  lstm_main<<<NBLK, NT, 0, stream>>>(x, W_aout, b_aout, W_fh, b_fh,
                                     W_iouh, b_iouh, W_oout, b_oout, ws, out);
}

// Round 14
// 203.633 us; speedup vs baseline: 1.5043x; 1.2889x over previous
//
#include <hip/hip_runtime.h>
#include <cstddef>

#define D   64
#define L   128
#define NT  256            // 4 waves per block
#define ROWS 16            // one M=16 MFMA tile per block
#define XSS 132            // padded floats (mult of 4 keeps float4 alignment)
#define HBS 72             // shorts
#define NBLK 512           // 8192 / 16
#define LOG2E 1.4426950408889634f

typedef __attribute__((ext_vector_type(8))) short short8;
typedef __attribute__((ext_vector_type(4))) float floatx4;
typedef __attribute__((ext_vector_type(2))) float f2;

__device__ __forceinline__ float fast_rcp(float x) {
#if defined(__has_builtin)
#if __has_builtin(__builtin_amdgcn_rcpf)
  return __builtin_amdgcn_rcpf(x);
#else
  return 1.0f / x;
#endif
#else
  return 1.0f / x;
#endif
}
__device__ __forceinline__ float ex2(float x) {
#if defined(__has_builtin)
#if __has_builtin(__builtin_amdgcn_exp2f)
  return __builtin_amdgcn_exp2f(x);
#else
  return __builtin_exp2f(x);
#endif
#else
  return __builtin_exp2f(x);
#endif
}
__device__ __forceinline__ f2 ex2_2(f2 v) { return (f2){ex2(v.x), ex2(v.y)}; }
__device__ __forceinline__ f2 rcp_2(f2 v) { return (f2){fast_rcp(v.x), fast_rcp(v.y)}; }
__device__ __forceinline__ float sig_plain(float x) {
  return fast_rcp(1.0f + ex2(-LOG2E * x));
}
__device__ __forceinline__ float tanh2(float G) {   // tanh(x), G = -2log2e*x
  return fmaf(2.0f, fast_rcp(1.0f + ex2(G)), -1.0f);
}
__device__ __forceinline__ unsigned short f2bf_rtne(float f) {
  unsigned int u = __float_as_uint(f);
  u += 0x7fffu + ((u >> 16) & 1u);
  return (unsigned short)(u >> 16);
}
__device__ __forceinline__ float bf2f(unsigned short s) {
  return __uint_as_float(((unsigned int)s) << 16);
}

// Persistent 16-row LSTM scan (R11 structure — empirical winner across 7
// structural alternatives: 512 blocks x 4 waves = 2 blocks/CU, 2 waves/SIMD;
// wave w owns d in [16w,16w+16) for all 4 gates -> gates register-resident,
// ONE barrier/step; single-bf16 W_hh = 8 MFMAs/wave/step; packed-fp32
// elementwise, merged 5-exp2/2-rcp algebra).
// R14 change: s_setprio shapes the barrier convoy — priority 1 across the
// latency-critical post-barrier head (A-frag ds_read + C-init + MFMA issue),
// priority 0 for the transcendental-throughput section (where the wave
// should yield issue slots to the co-resident block's head). Trans pipe is
// the busy floor (~896 cyc/SIMD/step at 16 cyc/wave-trans); the target is
// the ~1400 cyc/step rendezvous stall.
__global__ __launch_bounds__(NT, 2)
void lstm_main(const float* __restrict__ x,
               const float* __restrict__ W_num,
               const float* __restrict__ b_num,
               const float* __restrict__ W_ih,
               const float* __restrict__ W_hh,
               const float* __restrict__ b_ih,
               const float* __restrict__ b_hh,
               const float* __restrict__ W_aout,
               const float* __restrict__ b_aout,
               const float* __restrict__ W_fh,
               const float* __restrict__ b_fh,
               const float* __restrict__ W_iouh,
               const float* __restrict__ b_iouh,
               const float* __restrict__ W_oout,
               const float* __restrict__ b_oout,
               float* __restrict__ acc_out,   // [0..63]=fc, [64..127]=hs, [128]=ticket
               float* __restrict__ out)
{
  __shared__ __align__(16) float xs[ROWS * XSS];       // 8.25 KB (x; later h/h_hat)
  __shared__ __align__(16) short hb[2][ROWS * HBS];    // 4.5 KB double-buffered bf16 h
  __shared__ float sacc[2 * D];
  __shared__ float hobj[D];
  __shared__ int   is_last;

  const int tid  = threadIdx.x;
  const int w    = tid >> 6;
  const int lane = tid & 63;
  const int quad = lane >> 4;
  const int c16  = lane & 15;
  const int k0   = blockIdx.x * ROWS;
  const int dcol = w * 16 + c16;

  // ---- stage x tile (16 rows x 128), coalesced ----
  for (int i = tid; i < ROWS * (L / 4); i += NT) {
    int r = i >> 5, c4 = i & 31;
    float4 v = ((const float4*)(x + (size_t)(k0 + r) * L))[c4];
    float* dst = &xs[r * XSS + c4 * 4];
    dst[0] = v.x; dst[1] = v.y; dst[2] = v.z; dst[3] = v.w;
  }
  for (int i = tid; i < ROWS * HBS; i += NT) hb[0][i] = 0;

  // per-gate exp2 prescale (g-gate feeds tanh -> -2log2e)
  const float gscale[4] = {-LOG2E, -LOG2E, -2.0f * LOG2E, -LOG2E};

  // ---- rank-1 x-projection constants (prescaled), float4 loads ----
  float An[4], Bc[4];
#pragma unroll
  for (int g = 0; g < 4; ++g) {
    int j = g * 64 + dcol;
    const float4* wr = (const float4*)(W_ih + (size_t)j * (2 * D));
    float a = 0.0f, b = b_ih[j] + b_hh[j];
#pragma unroll
    for (int e4 = 0; e4 < 16; ++e4) {
      float4 wv = wr[e4];
      float4 wn = ((const float4*)W_num)[e4];
      float4 bn = ((const float4*)b_num)[e4];
      a = fmaf(wn.x, wv.x, a); a = fmaf(wn.y, wv.y, a);
      a = fmaf(wn.z, wv.z, a); a = fmaf(wn.w, wv.w, a);
      b = fmaf(bn.x, wv.x, b); b = fmaf(bn.y, wv.y, b);
      b = fmaf(bn.z, wv.z, b); b = fmaf(bn.w, wv.w, b);
    }
    An[g] = a * gscale[g]; Bc[g] = b * gscale[g];
  }

  // ---- W_hh B-fragments (prescaled, single RTNE bf16, constant) ----
  short8 Bf[4][2];
#pragma unroll
  for (int g = 0; g < 4; ++g) {
#pragma unroll
    for (int kk = 0; kk < 2; ++kk) {
      const float4* wp = (const float4*)(W_hh + (size_t)(g * 64 + dcol) * D
                                         + kk * 32 + quad * 8);
      float wv[8];
      float4 w0 = wp[0], w1 = wp[1];
      wv[0]=w0.x; wv[1]=w0.y; wv[2]=w0.z; wv[3]=w0.w;
      wv[4]=w1.x; wv[5]=w1.y; wv[6]=w1.z; wv[7]=w1.w;
      short8 hi8;
#pragma unroll
      for (int j = 0; j < 8; ++j)
        hi8[j] = (short)f2bf_rtne(wv[j] * gscale[g]);
      Bf[g][kk] = hi8;
    }
  }

  const f2 one2  = {1.0f, 1.0f};
  const f2 m2l2  = {-2.0f * LOG2E, -2.0f * LOG2E};
  f2 creg2[2] = {{0.f, 0.f}, {0.f, 0.f}};   // cell pairs (r0,r1),(r2,r3)
  f2 hreg2[2] = {{0.f, 0.f}, {0.f, 0.f}};
  __syncthreads();

  int p = 0;
  for (int t4 = 0; t4 < L; t4 += 4) {
    // 4 steps' worth of x per row in one b128 each
    float4 xq[4];
#pragma unroll
    for (int r = 0; r < 4; ++r)
      xq[r] = *(const float4*)&xs[(quad * 4 + r) * XSS + t4];
#pragma unroll
    for (int u = 0; u < 4; ++u) {
      // --- latency-critical head: boost priority so siblings reach the
      //     next barrier fast; co-resident block's trans yields to us ---
      __builtin_amdgcn_s_setprio(1);
      short8 ahi[2];
#pragma unroll
      for (int kk = 0; kk < 2; ++kk)
        ahi[kk] = *(const short8*)&hb[p][c16 * HBS + kk * 32 + quad * 8];
      f2 xv01 = {xq[0][u], xq[1][u]};
      f2 xv23 = {xq[2][u], xq[3][u]};
      floatx4 acc[4];
#pragma unroll
      for (int g = 0; g < 4; ++g) {
        f2 A2 = {An[g], An[g]}, B2 = {Bc[g], Bc[g]};
        f2 i01 = A2 * xv01 + B2;        // v_pk_fma_f32
        f2 i23 = A2 * xv23 + B2;
        acc[g] = (floatx4){i01.x, i01.y, i23.x, i23.y};
      }
#pragma unroll
      for (int kk = 0; kk < 2; ++kk) {
#pragma unroll
        for (int g = 0; g < 4; ++g)
          acc[g] = __builtin_amdgcn_mfma_f32_16x16x32_bf16(ahi[kk], Bf[g][kk], acc[g], 0, 0, 0);
      }
      // --- throughput-bound trans section: yield issue priority ---
      __builtin_amdgcn_s_setprio(0);
#pragma unroll
      for (int h = 0; h < 2; ++h) {
        f2 Gi = {acc[0][2*h], acc[0][2*h+1]};
        f2 Gf = {acc[1][2*h], acc[1][2*h+1]};
        f2 Gg = {acc[2][2*h], acc[2][2*h+1]};
        f2 Go = {acc[3][2*h], acc[3][2*h+1]};
        f2 Ei = ex2_2(Gi), Ef = ex2_2(Gf), Eg = ex2_2(Gg), Eo = ex2_2(Go);
        f2 pf = Ef + one2, pi = Ei + one2, pg = Eg + one2, mg = one2 - Eg;
        f2 pig = pi * pg;
        f2 num = creg2[h] * pig + mg * pf;
        f2 c2  = num * rcp_2(pf * pig);
        creg2[h] = c2;
        f2 Ec = ex2_2(c2 * m2l2);
        f2 po = Eo + one2, pc = Ec + one2, mc = one2 - Ec;
        f2 h2 = mc * rcp_2(po * pc);
        hreg2[h] = h2;
        int row0 = quad * 4 + 2 * h;
        hb[p ^ 1][row0 * HBS + dcol]       = (short)f2bf_rtne(h2.x);
        hb[p ^ 1][(row0 + 1) * HBS + dcol] = (short)f2bf_rtne(h2.y);
      }
      __syncthreads();
      p ^= 1;
    }
  }

  // unpack pair registers for the tail
  float creg[4] = {creg2[0].x, creg2[0].y, creg2[1].x, creg2[1].y};
  float hreg[4] = {hreg2[0].x, hreg2[0].y, hreg2[1].x, hreg2[1].y};

  // ---- tail: h_hat = h@W_aout.T+b ; f = h_hat@W_fh.T+b ; partial sums ----
  // x tile dead: xs[row][0..63] = h fp32, xs[row][64..127] = h_hat
#pragma unroll
  for (int r = 0; r < 4; ++r) xs[(quad * 4 + r) * XSS + dcol] = hreg[r];
  __syncthreads();

  float hhat[4];
#pragma unroll
  for (int r = 0; r < 4; ++r) {
    float a = b_aout[dcol];
    const float4* wa = (const float4*)(W_aout + (size_t)dcol * D);
    const float* hp = &xs[(quad * 4 + r) * XSS];
#pragma unroll
    for (int e4 = 0; e4 < 16; ++e4) {
      float4 wv = wa[e4];
      a = fmaf(wv.x, hp[e4*4+0], a); a = fmaf(wv.y, hp[e4*4+1], a);
      a = fmaf(wv.z, hp[e4*4+2], a); a = fmaf(wv.w, hp[e4*4+3], a);
    }
    hhat[r] = a;
  }
  __syncthreads();
#pragma unroll
  for (int r = 0; r < 4; ++r) xs[(quad * 4 + r) * XSS + 64 + dcol] = hhat[r];
  __syncthreads();

  float pfc = 0.0f, phs = 0.0f;
#pragma unroll
  for (int r = 0; r < 4; ++r) {
    float f = b_fh[dcol];
    const float4* wf = (const float4*)(W_fh + (size_t)dcol * D);
    const float* hp = &xs[(quad * 4 + r) * XSS + 64];
#pragma unroll
    for (int e4 = 0; e4 < 16; ++e4) {
      float4 wv = wf[e4];
      f = fmaf(wv.x, hp[e4*4+0], f); f = fmaf(wv.y, hp[e4*4+1], f);
      f = fmaf(wv.z, hp[e4*4+2], f); f = fmaf(wv.w, hp[e4*4+3], f);
    }
    pfc = fmaf(sig_plain(f), creg[r], pfc);
    phs += hhat[r];
  }
  pfc += __shfl_xor(pfc, 16); pfc += __shfl_xor(pfc, 32);
  phs += __shfl_xor(phs, 16); phs += __shfl_xor(phs, 32);
  if (quad == 0) {
    atomicAdd(acc_out + dcol, pfc);
    atomicAdd(acc_out + D + dcol, phs);
  }

  // ---- last-block finish ----
  __threadfence();
  if (tid == 0) {
    unsigned int prev = __hip_atomic_fetch_add((unsigned int*)(acc_out + 2 * D), 1u,
                                               __ATOMIC_ACQ_REL, __HIP_MEMORY_SCOPE_AGENT);
    is_last = (prev == NBLK - 1) ? 1 : 0;
  }
  __syncthreads();
  if (!is_last) return;
  __threadfence();
  if (tid < 2 * D)
    sacc[tid] = __hip_atomic_load(acc_out + tid, __ATOMIC_RELAXED, __HIP_MEMORY_SCOPE_AGENT);
  __syncthreads();
  if (tid < D) {
    const int d = tid;
    float vi = b_iouh[d], vo = b_iouh[D + d], vu = b_iouh[2 * D + d];
    for (int e = 0; e < D; ++e) {
      float hs = sacc[D + e];
      vi = fmaf(W_iouh[(size_t)d * D + e],           hs, vi);
      vo = fmaf(W_iouh[(size_t)(D + d) * D + e],     hs, vo);
      vu = fmaf(W_iouh[(size_t)(2 * D + d) * D + e], hs, vu);
    }
    float c_obj = sig_plain(vi) * tanh2(-2.0f * LOG2E * vu) + sacc[d];
    float h_obj = sig_plain(vo) * tanh2(-2.0f * LOG2E * c_obj);
    hobj[d] = h_obj;
    out[D + d] = c_obj;
  }
  __syncthreads();
  if (tid < D) {
    const int d = tid;
    float hh = b_oout[d];
    for (int e = 0; e < D; ++e) hh = fmaf(W_oout[(size_t)d * D + e], hobj[e], hh);
    out[d] = hh;
  }
}

extern "C" void kernel_launch(void* const* d_in, const int* in_sizes, int n_in,
                              void* d_out, int out_size, void* d_ws, size_t ws_size,
                              hipStream_t stream) {
  const float* x      = (const float*)d_in[0];
  const float* W_num  = (const float*)d_in[1];
  const float* b_num  = (const float*)d_in[2];
  const float* W_ih   = (const float*)d_in[3];
  const float* W_hh   = (const float*)d_in[4];
  const float* b_ih   = (const float*)d_in[5];
  const float* b_hh   = (const float*)d_in[6];
  const float* W_aout = (const float*)d_in[7];
  const float* b_aout = (const float*)d_in[8];
  const float* W_fh   = (const float*)d_in[9];
  const float* b_fh   = (const float*)d_in[10];
  const float* W_iouh = (const float*)d_in[11];
  const float* b_iouh = (const float*)d_in[12];
  const float* W_oout = (const float*)d_in[13];
  const float* b_oout = (const float*)d_in[14];
  float* acc = (float*)d_ws;
  float* out = (float*)d_out;

  hipMemsetAsync(d_ws, 0, (2 * D + 1) * sizeof(float), stream);
  lstm_main<<<NBLK, NT, 0, stream>>>(x, W_num, b_num, W_ih, W_hh, b_ih, b_hh,
                                     W_aout, b_aout, W_fh, b_fh,
                                     W_iouh, b_iouh, W_oout, b_oout, acc, out);
}